// Round 1
// baseline (661.162 us; speedup 1.0000x reference)
//
#include <hip/hip_runtime.h>
#include <cstdint>

#define B 64
#define L 512
#define EMB 400
#define H 256
#define NL 3
#define NE 512
#define MAXA 32

// ---------------------------------------------------------------------------
// Tiled fp32 GEMM config: BM=BN=64, BK=16, 256 threads (16x16), 4x4 micro-tile
// ---------------------------------------------------------------------------

// x[b,l,o] = sum_i W1[o,i] * Semb[b,i,l]   (Semb: [B][EMB][L], out X: [B*L][H])
__global__ __launch_bounds__(256) void k_conv_gemm(const float* __restrict__ Semb,
                                                   const float* __restrict__ W1,
                                                   float* __restrict__ X) {
  const int bx = blockIdx.x;        // 0..511 : b*8 + l-tile
  const int b  = bx >> 3;
  const int l0 = (bx & 7) * 64;
  const int n0 = blockIdx.y * 64;
  __shared__ float sa[16][68];
  __shared__ float sb[16][68];
  const int t = threadIdx.x;
  const int tx = t & 15, ty = t >> 4;
  float acc[4][4] = {};
  const float* sB = Semb + (size_t)b * EMB * L;
  for (int k0 = 0; k0 < EMB; k0 += 16) {
    { // A tile: sa[k][m] = Semb[b][k0+k][l0+m]  (contiguous in m)
      const int k = t >> 4, m4 = (t & 15) * 4;
      const float4 v = *(const float4*)(sB + (k0 + k) * L + l0 + m4);
      *(float4*)&sa[k][m4] = v;
    }
    { // B tile: sb[k][n] = W1[(n0+n)*EMB + k0+k]
      const int n = t >> 2, kk = (t & 3) * 4;
      const float4 v = *(const float4*)(W1 + (n0 + n) * EMB + k0 + kk);
      sb[kk][n] = v.x; sb[kk + 1][n] = v.y; sb[kk + 2][n] = v.z; sb[kk + 3][n] = v.w;
    }
    __syncthreads();
#pragma unroll
    for (int k = 0; k < 16; ++k) {
      const float4 av = *(const float4*)&sa[k][ty * 4];
      const float4 bv = *(const float4*)&sb[k][tx * 4];
      const float a_[4] = {av.x, av.y, av.z, av.w};
      const float b_[4] = {bv.x, bv.y, bv.z, bv.w};
#pragma unroll
      for (int i = 0; i < 4; ++i)
#pragma unroll
        for (int j = 0; j < 4; ++j) acc[i][j] = fmaf(a_[i], b_[j], acc[i][j]);
    }
    __syncthreads();
  }
  const int mbase = b * L + l0 + ty * 4;
#pragma unroll
  for (int i = 0; i < 4; ++i) {
    float4 v = make_float4(acc[i][0], acc[i][1], acc[i][2], acc[i][3]);
    *(float4*)(X + (size_t)(mbase + i) * H + n0 + tx * 4) = v;
  }
}

// Highway layer: out = sig(Wg x + bg) * (Wn x + bn) + (1-sig)*x,  x: [B*L][H]
__global__ __launch_bounds__(256) void k_highway(const float* __restrict__ Xin,
                                                 const float* __restrict__ Wg,
                                                 const float* __restrict__ bg,
                                                 const float* __restrict__ Wn,
                                                 const float* __restrict__ bn,
                                                 float* __restrict__ Xout) {
  const int m0 = blockIdx.x * 64;
  const int n0 = blockIdx.y * 64;
  __shared__ float sa[16][68];
  __shared__ float sg[16][68];
  __shared__ float sn[16][68];
  const int t = threadIdx.x;
  const int tx = t & 15, ty = t >> 4;
  float accg[4][4] = {}, accn[4][4] = {};
  for (int k0 = 0; k0 < H; k0 += 16) {
    { // A tile transpose-store: sa[k][m] = Xin[(m0+m)*H + k0+k]
      const int m = t >> 2, kk = (t & 3) * 4;
      const float4 v = *(const float4*)(Xin + (size_t)(m0 + m) * H + k0 + kk);
      sa[kk][m] = v.x; sa[kk + 1][m] = v.y; sa[kk + 2][m] = v.z; sa[kk + 3][m] = v.w;
    }
    {
      const int n = t >> 2, kk = (t & 3) * 4;
      const float4 vg = *(const float4*)(Wg + (n0 + n) * H + k0 + kk);
      sg[kk][n] = vg.x; sg[kk + 1][n] = vg.y; sg[kk + 2][n] = vg.z; sg[kk + 3][n] = vg.w;
      const float4 vn = *(const float4*)(Wn + (n0 + n) * H + k0 + kk);
      sn[kk][n] = vn.x; sn[kk + 1][n] = vn.y; sn[kk + 2][n] = vn.z; sn[kk + 3][n] = vn.w;
    }
    __syncthreads();
#pragma unroll
    for (int k = 0; k < 16; ++k) {
      const float4 av = *(const float4*)&sa[k][ty * 4];
      const float4 gv = *(const float4*)&sg[k][tx * 4];
      const float4 nv = *(const float4*)&sn[k][tx * 4];
      const float a_[4] = {av.x, av.y, av.z, av.w};
      const float g_[4] = {gv.x, gv.y, gv.z, gv.w};
      const float n_[4] = {nv.x, nv.y, nv.z, nv.w};
#pragma unroll
      for (int i = 0; i < 4; ++i)
#pragma unroll
        for (int j = 0; j < 4; ++j) {
          accg[i][j] = fmaf(a_[i], g_[j], accg[i][j]);
          accn[i][j] = fmaf(a_[i], n_[j], accn[i][j]);
        }
    }
    __syncthreads();
  }
#pragma unroll
  for (int i = 0; i < 4; ++i) {
    const int m = m0 + ty * 4 + i;
    const float4 xin = *(const float4*)(Xin + (size_t)m * H + n0 + tx * 4);
    const float xi[4] = {xin.x, xin.y, xin.z, xin.w};
    float r[4];
#pragma unroll
    for (int j = 0; j < 4; ++j) {
      const int o = n0 + tx * 4 + j;
      const float g = 1.f / (1.f + __expf(-(accg[i][j] + bg[o])));
      r[j] = g * (accn[i][j] + bn[o]) + (1.f - g) * xi[j];
    }
    *(float4*)(Xout + (size_t)m * H + n0 + tx * 4) = make_float4(r[0], r[1], r[2], r[3]);
  }
}

// GCN dense part: Out = relu((T @ W^T + 2b) * rden),  T: [B*L][H]
__global__ __launch_bounds__(256) void k_gcn_gemm(const float* __restrict__ T,
                                                  const float* __restrict__ W,
                                                  const float* __restrict__ bias,
                                                  const float* __restrict__ rden,
                                                  float* __restrict__ Out) {
  const int m0 = blockIdx.x * 64;
  const int n0 = blockIdx.y * 64;
  __shared__ float sa[16][68];
  __shared__ float sb[16][68];
  const int t = threadIdx.x;
  const int tx = t & 15, ty = t >> 4;
  float acc[4][4] = {};
  for (int k0 = 0; k0 < H; k0 += 16) {
    {
      const int m = t >> 2, kk = (t & 3) * 4;
      const float4 v = *(const float4*)(T + (size_t)(m0 + m) * H + k0 + kk);
      sa[kk][m] = v.x; sa[kk + 1][m] = v.y; sa[kk + 2][m] = v.z; sa[kk + 3][m] = v.w;
    }
    {
      const int n = t >> 2, kk = (t & 3) * 4;
      const float4 v = *(const float4*)(W + (n0 + n) * H + k0 + kk);
      sb[kk][n] = v.x; sb[kk + 1][n] = v.y; sb[kk + 2][n] = v.z; sb[kk + 3][n] = v.w;
    }
    __syncthreads();
#pragma unroll
    for (int k = 0; k < 16; ++k) {
      const float4 av = *(const float4*)&sa[k][ty * 4];
      const float4 bv = *(const float4*)&sb[k][tx * 4];
      const float a_[4] = {av.x, av.y, av.z, av.w};
      const float b_[4] = {bv.x, bv.y, bv.z, bv.w};
#pragma unroll
      for (int i = 0; i < 4; ++i)
#pragma unroll
        for (int j = 0; j < 4; ++j) acc[i][j] = fmaf(a_[i], b_[j], acc[i][j]);
    }
    __syncthreads();
  }
#pragma unroll
  for (int i = 0; i < 4; ++i) {
    const int m = m0 + ty * 4 + i;
    const float rd = rden[m];
    float r[4];
#pragma unroll
    for (int j = 0; j < 4; ++j) {
      const int o = n0 + tx * 4 + j;
      r[j] = fmaxf((acc[i][j] + 2.f * bias[o]) * rd, 0.f);
    }
    *(float4*)(Out + (size_t)m * H + n0 + tx * 4) = make_float4(r[0], r[1], r[2], r[3]);
  }
}

// Build dedup'd adjacency bitmap (handles duplicate edges like .set(1.0))
__global__ void k_edges(const int* __restrict__ edges, unsigned* __restrict__ bm) {
  const int t = blockIdx.x * 256 + threadIdx.x;   // < B*NE
  const int b = t >> 9, e = t & 511;
  const int u = edges[(size_t)(b * NE + e) * 2 + 0];
  const int v = edges[(size_t)(b * NE + e) * 2 + 1];
  atomicOr(&bm[(size_t)(b * L + u) * 16 + (v >> 5)], 1u << (v & 31));
  atomicOr(&bm[(size_t)(b * L + v) * 16 + (u >> 5)], 1u << (u & 31));
}

// rden[m] = 1 / (1 + rowsum(adj))
__global__ void k_rden(const unsigned* __restrict__ bm, float* __restrict__ rden) {
  const int m = blockIdx.x * 256 + threadIdx.x;   // < B*L
  const uint4* p = (const uint4*)(bm + (size_t)m * 16);
  int c = 0;
#pragma unroll
  for (int w = 0; w < 4; ++w) {
    const uint4 v = p[w];
    c += __popc(v.x) + __popc(v.y) + __popc(v.z) + __popc(v.w);
  }
  rden[m] = 1.f / (1.f + (float)c);
}

// T[m,:] = h[m,:] + sum_{s in adj row} h[s,:]   (block per token, thread per channel)
__global__ __launch_bounds__(256) void k_gather(const unsigned* __restrict__ bm,
                                                const float* __restrict__ h,
                                                float* __restrict__ T) {
  const int m = blockIdx.x;     // b*L + l
  const int b = m >> 9;
  __shared__ unsigned w[16];
  const int t = threadIdx.x;
  if (t < 16) w[t] = bm[(size_t)m * 16 + t];
  __syncthreads();
  float acc = h[(size_t)m * H + t];
  for (int wi = 0; wi < 16; ++wi) {
    unsigned bits = w[wi];
    while (bits) {
      const int bit = __ffs(bits) - 1;
      bits &= bits - 1;
      const int s = wi * 32 + bit;
      acc += h[(size_t)(b * L + s) * H + t];
    }
  }
  T[(size_t)m * H + t] = acc;
}

// y[m] = relu(sum_c cat[m,c]*conv_W[c] + conv_b), wave per token
__global__ __launch_bounds__(256) void k_y(const float* __restrict__ O0,
                                           const float* __restrict__ O1,
                                           const float* __restrict__ O2,
                                           const float* __restrict__ cw,
                                           const float* __restrict__ cb,
                                           float* __restrict__ y) {
  const int wid = (blockIdx.x << 2) | (threadIdx.x >> 6);   // token 0..B*L-1
  const int lane = threadIdx.x & 63;
  const float* Os[3] = {O0, O1, O2};
  float acc = 0.f;
#pragma unroll
  for (int p = 0; p < 3; ++p) {
    const float* O = Os[p];
#pragma unroll
    for (int j = 0; j < 4; ++j) {
      const int c = j * 64 + lane;
      acc += O[(size_t)wid * H + c] * cw[p * H + c];
    }
  }
  for (int off = 32; off > 0; off >>= 1) acc += __shfl_down(acc, off);
  if (lane == 0) y[wid] = fmaxf(acc + cb[0], 0.f);
}

// logits[b,m] = maskS ? (sum_l y[b,l]*lin_W[m,l] + lin_b[m]) : -1e30
__global__ __launch_bounds__(256) void k_logits(const float* __restrict__ y,
                                                const float* __restrict__ lw,
                                                const float* __restrict__ lb,
                                                const int* __restrict__ wids,
                                                float* __restrict__ out) {
  const int b = blockIdx.x >> 1;
  const int m = ((blockIdx.x & 1) << 8) + threadIdx.x;
  __shared__ float ys[512];
  ys[threadIdx.x] = y[(size_t)b * L + threadIdx.x];
  ys[threadIdx.x + 256] = y[(size_t)b * L + 256 + threadIdx.x];
  __syncthreads();
  float acc = lb[m];
  const float4* wr = (const float4*)(lw + (size_t)m * L);
#pragma unroll 4
  for (int l4 = 0; l4 < 128; ++l4) {
    const float4 w4 = wr[l4];
    acc += ys[l4 * 4] * w4.x + ys[l4 * 4 + 1] * w4.y + ys[l4 * 4 + 2] * w4.z + ys[l4 * 4 + 3] * w4.w;
  }
  out[(size_t)b * L + m] = (wids[(size_t)b * L + m] != 0) ? acc : -1.0e30f;
}

__global__ void k_maskA(const int* __restrict__ y1, const int* __restrict__ y2,
                        float* __restrict__ out) {
  const int t = blockIdx.x * 256 + threadIdx.x;   // < B*MAXA
  const int b = t >> 5, j = t & 31;
  out[t] = (y1[b] + j <= y2[b]) ? 1.0f : 0.0f;
}

extern "C" void kernel_launch(void* const* d_in, const int* in_sizes, int n_in,
                              void* d_out, int out_size, void* d_ws, size_t ws_size,
                              hipStream_t stream) {
  (void)in_sizes; (void)n_in; (void)out_size; (void)ws_size;
  const float* Semb      = (const float*)d_in[0];
  const int*   wids      = (const int*)d_in[1];
  const int*   y1        = (const int*)d_in[2];
  const int*   y2        = (const int*)d_in[3];
  const int*   edges     = (const int*)d_in[4];
  const float* W1        = (const float*)d_in[5];
  const float* hw_lin_W  = (const float*)d_in[6];
  const float* hw_lin_b  = (const float*)d_in[7];
  const float* hw_gate_W = (const float*)d_in[8];
  const float* hw_gate_b = (const float*)d_in[9];
  const float* gcn_W     = (const float*)d_in[10];
  const float* gcn_b     = (const float*)d_in[11];
  const float* conv_W    = (const float*)d_in[12];
  const float* conv_b    = (const float*)d_in[13];
  const float* lin_W     = (const float*)d_in[14];
  const float* lin_b     = (const float*)d_in[15];
  float* out = (float*)d_out;

  char* ws = (char*)d_ws;
  const size_t SZ = (size_t)B * L * H * sizeof(float);      // 33,554,432
  float*    P0   = (float*)(ws);
  float*    P1   = (float*)(ws + SZ);
  float*    O0   = (float*)(ws + 2 * SZ);
  float*    O1   = (float*)(ws + 3 * SZ);
  float*    O2   = (float*)(ws + 4 * SZ);
  unsigned* bm   = (unsigned*)(ws + 5 * SZ);                // 2 MB bitmap
  float*    rden = (float*)(ws + 5 * SZ + 2097152);
  float*    yv   = (float*)(ws + 5 * SZ + 2097152 + 131072);

  hipMemsetAsync(bm, 0, (size_t)B * L * 16 * sizeof(unsigned), stream);
  k_edges<<<dim3(B * NE / 256), 256, 0, stream>>>(edges, bm);
  k_rden<<<dim3(B * L / 256), 256, 0, stream>>>(bm, rden);

  k_conv_gemm<<<dim3(B * L / 64, H / 64), 256, 0, stream>>>(Semb, W1, P0);
  k_highway<<<dim3(B * L / 64, H / 64), 256, 0, stream>>>(P0, hw_gate_W, hw_gate_b,
                                                          hw_lin_W, hw_lin_b, P1);
  k_highway<<<dim3(B * L / 64, H / 64), 256, 0, stream>>>(P1, hw_gate_W + H * H, hw_gate_b + H,
                                                          hw_lin_W + H * H, hw_lin_b + H, P0);

  const float* hin = P0;
  float* outs[3] = {O0, O1, O2};
  for (int l = 0; l < NL; ++l) {
    k_gather<<<dim3(B * L), 256, 0, stream>>>(bm, hin, P1);
    k_gcn_gemm<<<dim3(B * L / 64, H / 64), 256, 0, stream>>>(P1, gcn_W + l * H * H,
                                                             gcn_b + l * H, rden, outs[l]);
    hin = outs[l];
  }

  k_y<<<dim3(B * L / 4), 256, 0, stream>>>(O0, O1, O2, conv_W, conv_b, yv);
  k_logits<<<dim3(B * 2), 256, 0, stream>>>(yv, lin_W, lin_b, wids, out);
  k_maskA<<<dim3(B * MAXA / 256), 256, 0, stream>>>(y1, y2, out + B * L);
}

// Round 2
// 274.253 us; speedup vs baseline: 2.4108x; 2.4108x over previous
//
#include <hip/hip_runtime.h>
#include <cstdint>

#define B 64
#define L 512
#define EMB 400
#define KPAD 416
#define H 256
#define NL 3
#define NE 512
#define MAXA 32
#define M_TOT (B * L)

typedef unsigned short u16;
typedef float f32x4 __attribute__((ext_vector_type(4)));
typedef short short8 __attribute__((ext_vector_type(8)));
typedef u16 u16x8 __attribute__((ext_vector_type(8)));

__device__ __forceinline__ float b2f(u16 u) {
  unsigned v = ((unsigned)u) << 16;
  return __builtin_bit_cast(float, v);
}
__device__ __forceinline__ u16 f2b(float f) {
  unsigned u = __builtin_bit_cast(unsigned, f);
  unsigned r = (u + 0x7fffu + ((u >> 16) & 1u)) >> 16;
  return (u16)r;
}

#define GL16(g, l)                                                              \
  __builtin_amdgcn_global_load_lds((const __attribute__((address_space(1))) void*)(g), \
                                   (__attribute__((address_space(3))) void*)(l), 16, 0, 0)

// ---------------------------------------------------------------------------
// bf16 MFMA GEMM: C[M_TOT x 256] = A[M_TOT x K] * Bw[256 x K]^T
// 128x128 tile, BK=32, 256 threads = 4 waves (2x2), 64x64 per wave, 4x4 frags.
// EPI: 0 = plain bf16 store (conv)
//      1 = highway: out = sig(acc+b1) * (acc2+b2) + (1-sig)*Xres
//      2 = gcn:     out = relu((acc + 2*b1) * rden[row])
// ---------------------------------------------------------------------------
template <int EPI>
__global__ __launch_bounds__(256, 2) void gemm128(const u16* __restrict__ A,
                                                  const u16* __restrict__ Bw,
                                                  const u16* __restrict__ B2w, int K,
                                                  const float* __restrict__ bias1,
                                                  const float* __restrict__ bias2,
                                                  const u16* __restrict__ Xres,
                                                  const float* __restrict__ rden,
                                                  u16* __restrict__ Out) {
  __shared__ u16 Al[128 * 32];
  __shared__ u16 Bl[128 * 32];
  __shared__ u16 Cl[128 * 32];

  const int t = threadIdx.x;
  const int wid = t >> 6, lane = t & 63;
  const int wm = wid >> 1, wn = wid & 1;
  const int m0 = blockIdx.x * 128, n0 = blockIdx.y * 128;

  // staging geometry: chunk ch in [0,512): row = ch>>2, kseg = ch&3 (8 elems)
  const int r4 = t >> 2, kseg = t & 3;
  u16* alb1 = Al + (size_t)(wid * 64) * 8;
  u16* alb2 = Al + (size_t)(256 + wid * 64) * 8;
  u16* blb1 = Bl + (size_t)(wid * 64) * 8;
  u16* blb2 = Bl + (size_t)(256 + wid * 64) * 8;
  u16* clb1 = Cl + (size_t)(wid * 64) * 8;
  u16* clb2 = Cl + (size_t)(256 + wid * 64) * 8;

  f32x4 acc[4][4] = {};
  f32x4 acc2[4][4] = {};

  const int fr = lane & 15, kg = lane >> 4;
  const int nk = K >> 5;

  for (int kk = 0; kk < nk; ++kk) {
    const int k0 = kk * 32;
    {
      const u16* ga = A + (size_t)(m0 + r4) * K + k0 + kseg * 8;
      GL16(ga, alb1);
      GL16(ga + (size_t)64 * K, alb2);
      const u16* gb = Bw + (size_t)(n0 + r4) * K + k0 + kseg * 8;
      GL16(gb, blb1);
      GL16(gb + (size_t)64 * K, blb2);
      if constexpr (EPI == 1) {
        const u16* gc = B2w + (size_t)(n0 + r4) * K + k0 + kseg * 8;
        GL16(gc, clb1);
        GL16(gc + (size_t)64 * K, clb2);
      }
    }
    __syncthreads();

    short8 af[4], bf[4], cf[4];
#pragma unroll
    for (int i = 0; i < 4; ++i) {
      af[i] = *(const short8*)(Al + ((size_t)(wm * 64 + i * 16 + fr) * 4 + kg) * 8);
      bf[i] = *(const short8*)(Bl + ((size_t)(wn * 64 + i * 16 + fr) * 4 + kg) * 8);
      if constexpr (EPI == 1)
        cf[i] = *(const short8*)(Cl + ((size_t)(wn * 64 + i * 16 + fr) * 4 + kg) * 8);
    }
#pragma unroll
    for (int mi = 0; mi < 4; ++mi)
#pragma unroll
      for (int ni = 0; ni < 4; ++ni) {
        acc[mi][ni] = __builtin_amdgcn_mfma_f32_16x16x32_bf16(af[mi], bf[ni], acc[mi][ni], 0, 0, 0);
        if constexpr (EPI == 1)
          acc2[mi][ni] =
              __builtin_amdgcn_mfma_f32_16x16x32_bf16(af[mi], cf[ni], acc2[mi][ni], 0, 0, 0);
      }
    __syncthreads();
  }

  // epilogue: C/D mapping col = lane&15, row = (lane>>4)*4 + reg  [m89-verified]
  const int r0 = m0 + wm * 64 + kg * 4;
  const int c0 = n0 + wn * 64 + fr;
#pragma unroll
  for (int ni = 0; ni < 4; ++ni) {
    const int col = c0 + ni * 16;
    float b1 = 0.f, b2 = 0.f;
    if constexpr (EPI == 1) { b1 = bias1[col]; b2 = bias2[col]; }
    if constexpr (EPI == 2) { b1 = 2.f * bias1[col]; }
#pragma unroll
    for (int mi = 0; mi < 4; ++mi) {
#pragma unroll
      for (int r = 0; r < 4; ++r) {
        const int row = r0 + mi * 16 + r;
        const float v = acc[mi][ni][r];
        if constexpr (EPI == 0) {
          Out[(size_t)row * H + col] = f2b(v);
        } else if constexpr (EPI == 1) {
          const float g = 1.f / (1.f + __expf(-(v + b1)));
          const float nn = acc2[mi][ni][r] + b2;
          const float x = b2f(Xres[(size_t)row * H + col]);
          Out[(size_t)row * H + col] = f2b(g * nn + (1.f - g) * x);
        } else {
          const float s = (v + b1) * rden[row];
          Out[(size_t)row * H + col] = f2b(s > 0.f ? s : 0.f);
        }
      }
    }
  }
}

// ---------------------------------------------------------------------------
// Semb [B][EMB][L] fp32 -> A0 [B*L][KPAD] bf16 (transpose + pad 400->416)
// grid (B, 7, 8), block 256, 64x64 tile via LDS
// ---------------------------------------------------------------------------
__global__ __launch_bounds__(256) void k_sembT(const float* __restrict__ Semb,
                                               u16* __restrict__ A0) {
  const int b = blockIdx.x, e0 = blockIdx.y * 64, l0 = blockIdx.z * 64;
  __shared__ u16 tile[64][72];
  const int t = threadIdx.x;
  {
    const int er = t >> 2, ls = (t & 3) * 16;
    if (e0 + er < EMB) {
      const float* src = Semb + ((size_t)b * EMB + e0 + er) * L + l0 + ls;
#pragma unroll
      for (int i = 0; i < 4; ++i) {
        const float4 v = *(const float4*)(src + i * 4);
        tile[er][ls + i * 4 + 0] = f2b(v.x);
        tile[er][ls + i * 4 + 1] = f2b(v.y);
        tile[er][ls + i * 4 + 2] = f2b(v.z);
        tile[er][ls + i * 4 + 3] = f2b(v.w);
      }
    } else {
#pragma unroll
      for (int i = 0; i < 16; ++i) tile[er][ls + i] = 0;
    }
  }
  __syncthreads();
  {
    const int lr = t >> 2, es = (t & 3) * 16;
    if (e0 + es < KPAD) {
      u16x8 v0, v1;
#pragma unroll
      for (int i = 0; i < 8; ++i) v0[i] = tile[es + i][lr];
#pragma unroll
      for (int i = 0; i < 8; ++i) v1[i] = tile[es + 8 + i][lr];
      u16* dst = A0 + (size_t)(b * L + l0 + lr) * KPAD + e0 + es;
      *(u16x8*)dst = v0;
      *(u16x8*)(dst + 8) = v1;
    }
  }
}

// generic fp32 -> bf16
__global__ void k_cvt(const float* __restrict__ in, u16* __restrict__ out, int n) {
  const int i = blockIdx.x * 256 + threadIdx.x;
  if (i < n) out[i] = f2b(in[i]);
}

// W1 [256][400] fp32 -> [256][416] bf16 padded
__global__ void k_cvt_w1(const float* __restrict__ W1, u16* __restrict__ out) {
  const int i = blockIdx.x * 256 + threadIdx.x;  // < 256*416
  const int o = i / KPAD, k = i - o * KPAD;
  out[i] = (k < EMB) ? f2b(W1[o * EMB + k]) : (u16)0;
}

// dedup'd adjacency bitmap
__global__ void k_edges(const int* __restrict__ edges, unsigned* __restrict__ bm) {
  const int t = blockIdx.x * 256 + threadIdx.x;
  const int b = t >> 9, e = t & 511;
  const int u = edges[(size_t)(b * NE + e) * 2 + 0];
  const int v = edges[(size_t)(b * NE + e) * 2 + 1];
  atomicOr(&bm[(size_t)(b * L + u) * 16 + (v >> 5)], 1u << (v & 31));
  atomicOr(&bm[(size_t)(b * L + v) * 16 + (u >> 5)], 1u << (u & 31));
}

__global__ void k_rden(const unsigned* __restrict__ bm, float* __restrict__ rden) {
  const int m = blockIdx.x * 256 + threadIdx.x;
  const uint4* p = (const uint4*)(bm + (size_t)m * 16);
  int c = 0;
#pragma unroll
  for (int w = 0; w < 4; ++w) {
    const uint4 v = p[w];
    c += __popc(v.x) + __popc(v.y) + __popc(v.z) + __popc(v.w);
  }
  rden[m] = 1.f / (1.f + (float)c);
}

// T[m,:] = h[m,:] + sum_{s in adj row} h[s,:]  (bf16 in/out, fp32 accum)
__global__ __launch_bounds__(256) void k_gather(const unsigned* __restrict__ bm,
                                                const u16* __restrict__ h,
                                                u16* __restrict__ T) {
  const int m = blockIdx.x;
  const int b = m >> 9;
  __shared__ unsigned w[16];
  const int t = threadIdx.x;
  if (t < 16) w[t] = bm[(size_t)m * 16 + t];
  __syncthreads();
  float acc = b2f(h[(size_t)m * H + t]);
  for (int wi = 0; wi < 16; ++wi) {
    unsigned bits = w[wi];
    while (bits) {
      const int bit = __ffs(bits) - 1;
      bits &= bits - 1;
      const int s = wi * 32 + bit;
      acc += b2f(h[(size_t)(b * L + s) * H + t]);
    }
  }
  T[(size_t)m * H + t] = f2b(acc);
}

// y[m] = relu(sum_c cat[m,c]*conv_W[c] + conv_b), wave per token
__global__ __launch_bounds__(256) void k_y(const u16* __restrict__ O0,
                                           const u16* __restrict__ O1,
                                           const u16* __restrict__ O2,
                                           const float* __restrict__ cw,
                                           const float* __restrict__ cb,
                                           float* __restrict__ y) {
  const int wid = (blockIdx.x << 2) | (threadIdx.x >> 6);
  const int lane = threadIdx.x & 63;
  const u16* Os[3] = {O0, O1, O2};
  float acc = 0.f;
#pragma unroll
  for (int p = 0; p < 3; ++p) {
    const u16* O = Os[p];
#pragma unroll
    for (int j = 0; j < 4; ++j) {
      const int c = j * 64 + lane;
      acc += b2f(O[(size_t)wid * H + c]) * cw[p * H + c];
    }
  }
  for (int off = 32; off > 0; off >>= 1) acc += __shfl_down(acc, off);
  if (lane == 0) y[wid] = fmaxf(acc + cb[0], 0.f);
}

__global__ __launch_bounds__(256) void k_logits(const float* __restrict__ y,
                                                const float* __restrict__ lw,
                                                const float* __restrict__ lb,
                                                const int* __restrict__ wids,
                                                float* __restrict__ out) {
  const int b = blockIdx.x >> 1;
  const int m = ((blockIdx.x & 1) << 8) + threadIdx.x;
  __shared__ float ys[512];
  ys[threadIdx.x] = y[(size_t)b * L + threadIdx.x];
  ys[threadIdx.x + 256] = y[(size_t)b * L + 256 + threadIdx.x];
  __syncthreads();
  float acc = lb[m];
  const float4* wr = (const float4*)(lw + (size_t)m * L);
#pragma unroll 4
  for (int l4 = 0; l4 < 128; ++l4) {
    const float4 w4 = wr[l4];
    acc += ys[l4 * 4] * w4.x + ys[l4 * 4 + 1] * w4.y + ys[l4 * 4 + 2] * w4.z +
           ys[l4 * 4 + 3] * w4.w;
  }
  out[(size_t)b * L + m] = (wids[(size_t)b * L + m] != 0) ? acc : -1.0e30f;
}

__global__ void k_maskA(const int* __restrict__ y1, const int* __restrict__ y2,
                        float* __restrict__ out) {
  const int t = blockIdx.x * 256 + threadIdx.x;
  const int b = t >> 5, j = t & 31;
  out[t] = (y1[b] + j <= y2[b]) ? 1.0f : 0.0f;
}

extern "C" void kernel_launch(void* const* d_in, const int* in_sizes, int n_in,
                              void* d_out, int out_size, void* d_ws, size_t ws_size,
                              hipStream_t stream) {
  (void)in_sizes; (void)n_in; (void)out_size; (void)ws_size;
  const float* Semb      = (const float*)d_in[0];
  const int*   wids      = (const int*)d_in[1];
  const int*   y1        = (const int*)d_in[2];
  const int*   y2        = (const int*)d_in[3];
  const int*   edges     = (const int*)d_in[4];
  const float* W1        = (const float*)d_in[5];
  const float* hw_lin_W  = (const float*)d_in[6];
  const float* hw_lin_b  = (const float*)d_in[7];
  const float* hw_gate_W = (const float*)d_in[8];
  const float* hw_gate_b = (const float*)d_in[9];
  const float* gcn_W     = (const float*)d_in[10];
  const float* gcn_b     = (const float*)d_in[11];
  const float* conv_W    = (const float*)d_in[12];
  const float* conv_b    = (const float*)d_in[13];
  const float* lin_W     = (const float*)d_in[14];
  const float* lin_b     = (const float*)d_in[15];
  float* out = (float*)d_out;

  char* ws = (char*)d_ws;
  const size_t SZA = (size_t)M_TOT * KPAD * 2;   // 27,262,976
  const size_t SZX = (size_t)M_TOT * H * 2;      // 16,777,216
  u16* A0   = (u16*)(ws);
  u16* P0b  = (u16*)(ws + SZA);
  u16* P1b  = (u16*)(ws + SZA + SZX);
  u16* O0   = (u16*)(ws + SZA + 2 * SZX);
  u16* O1   = (u16*)(ws + SZA + 3 * SZX);
  u16* O2   = (u16*)(ws + SZA + 4 * SZX);
  char* wp  = ws + SZA + 5 * SZX;
  u16* W1b  = (u16*)(wp);                         // 256*416*2   = 212,992
  u16* HWGb = (u16*)(wp + 212992);                // 2*256*256*2 = 262,144
  u16* HWLb = (u16*)(wp + 212992 + 262144);       // 262,144
  u16* GCNb = (u16*)(wp + 212992 + 2 * 262144);   // 3*256*256*2 = 393,216
  char* sp  = wp + 212992 + 2 * 262144 + 393216;
  unsigned* bm   = (unsigned*)(sp);               // 2 MB
  float*    rden = (float*)(sp + 2097152);
  float*    yv   = (float*)(sp + 2097152 + 131072);

  // adjacency
  hipMemsetAsync(bm, 0, (size_t)B * L * 16 * sizeof(unsigned), stream);
  k_edges<<<dim3(B * NE / 256), 256, 0, stream>>>(edges, bm);
  k_rden<<<dim3(B * L / 256), 256, 0, stream>>>(bm, rden);

  // conversions
  k_cvt_w1<<<dim3(256 * KPAD / 256), 256, 0, stream>>>(W1, W1b);
  k_cvt<<<dim3(2 * H * H / 256), 256, 0, stream>>>(hw_gate_W, HWGb, 2 * H * H);
  k_cvt<<<dim3(2 * H * H / 256), 256, 0, stream>>>(hw_lin_W, HWLb, 2 * H * H);
  k_cvt<<<dim3(NL * H * H / 256), 256, 0, stream>>>(gcn_W, GCNb, NL * H * H);
  k_sembT<<<dim3(B, 7, 8), 256, 0, stream>>>(Semb, A0);

  // conv 1x1: X = A0 @ W1b^T
  gemm128<0><<<dim3(M_TOT / 128, 2), 256, 0, stream>>>(A0, W1b, nullptr, KPAD,
                                                       nullptr, nullptr, nullptr, nullptr, P0b);
  // highway x2 (fused gate+nonlin)
  gemm128<1><<<dim3(M_TOT / 128, 2), 256, 0, stream>>>(P0b, HWGb, HWLb, H,
                                                       hw_gate_b, hw_lin_b, P0b, nullptr, P1b);
  gemm128<1><<<dim3(M_TOT / 128, 2), 256, 0, stream>>>(P1b, HWGb + H * H, HWLb + H * H, H,
                                                       hw_gate_b + H, hw_lin_b + H, P1b, nullptr,
                                                       P0b);
  // GCN layers
  const u16* hin = P0b;
  u16* outs[3] = {O0, O1, O2};
  for (int l = 0; l < NL; ++l) {
    k_gather<<<dim3(M_TOT), 256, 0, stream>>>(bm, hin, P1b);
    gemm128<2><<<dim3(M_TOT / 128, 2), 256, 0, stream>>>(P1b, GCNb + l * H * H, nullptr, H,
                                                         gcn_b + l * H, nullptr, nullptr, rden,
                                                         outs[l]);
    hin = outs[l];
  }

  // head
  k_y<<<dim3(M_TOT / 4), 256, 0, stream>>>(O0, O1, O2, conv_W, conv_b, yv);
  k_logits<<<dim3(B * 2), 256, 0, stream>>>(yv, lin_W, lin_b, wids, out);
  k_maskA<<<dim3(B * MAXA / 256), 256, 0, stream>>>(y1, y2, out + B * L);
}

// Round 3
// 193.659 us; speedup vs baseline: 3.4141x; 1.4162x over previous
//
#include <hip/hip_runtime.h>
#include <cstdint>

#define B 64
#define L 512
#define EMB 400
#define KPAD 416
#define H 256
#define NL 3
#define NE 512
#define MAXA 32
#define M_TOT (B * L)

typedef unsigned short u16;
typedef float f32x4 __attribute__((ext_vector_type(4)));
typedef short short8 __attribute__((ext_vector_type(8)));
typedef u16 u16x8 __attribute__((ext_vector_type(8)));

__device__ __forceinline__ float b2f(u16 u) {
  unsigned v = ((unsigned)u) << 16;
  return __builtin_bit_cast(float, v);
}
__device__ __forceinline__ u16 f2b(float f) {
  unsigned u = __builtin_bit_cast(unsigned, f);
  unsigned r = (u + 0x7fffu + ((u >> 16) & 1u)) >> 16;
  return (u16)r;
}

#define GL16(g, l)                                                              \
  __builtin_amdgcn_global_load_lds((const __attribute__((address_space(1))) void*)(g), \
                                   (__attribute__((address_space(3))) void*)(l), 16, 0, 0)

// ---------------------------------------------------------------------------
// bf16 MFMA GEMM: C[M_TOT x 256] = A[M_TOT x K] * Bw[256 x K]^T
// 128x128 tile, BK=32, 256 threads = 4 waves (2x2), 64x64 per wave, 4x4 frags.
// EPI: 0 = plain bf16 store (conv)
//      1 = highway: out = sig(acc+b1) * (acc2+b2) + (1-sig)*Xres
//      2 = gcn:     out = relu((acc + 2*b1) * rden[row]); yv[row] += out.cw
// ---------------------------------------------------------------------------
template <int EPI>
__global__ __launch_bounds__(256, 2) void gemm128(const u16* __restrict__ A,
                                                  const u16* __restrict__ Bw,
                                                  const u16* __restrict__ B2w, int K,
                                                  const float* __restrict__ bias1,
                                                  const float* __restrict__ bias2,
                                                  const u16* __restrict__ Xres,
                                                  const float* __restrict__ rden,
                                                  const float* __restrict__ cw,
                                                  float* __restrict__ yv,
                                                  u16* __restrict__ Out) {
  __shared__ u16 Al[128 * 32];
  __shared__ u16 Bl[128 * 32];
  __shared__ u16 Cl[128 * 32];

  const int t = threadIdx.x;
  const int wid = t >> 6, lane = t & 63;
  const int wm = wid >> 1, wn = wid & 1;
  const int m0 = blockIdx.x * 128, n0 = blockIdx.y * 128;

  const int r4 = t >> 2, kseg = t & 3;
  u16* alb1 = Al + (size_t)(wid * 64) * 8;
  u16* alb2 = Al + (size_t)(256 + wid * 64) * 8;
  u16* blb1 = Bl + (size_t)(wid * 64) * 8;
  u16* blb2 = Bl + (size_t)(256 + wid * 64) * 8;
  u16* clb1 = Cl + (size_t)(wid * 64) * 8;
  u16* clb2 = Cl + (size_t)(256 + wid * 64) * 8;

  f32x4 acc[4][4] = {};
  f32x4 acc2[4][4] = {};

  const int fr = lane & 15, kg = lane >> 4;
  const int nk = K >> 5;

  for (int kk = 0; kk < nk; ++kk) {
    const int k0 = kk * 32;
    {
      const u16* ga = A + (size_t)(m0 + r4) * K + k0 + kseg * 8;
      GL16(ga, alb1);
      GL16(ga + (size_t)64 * K, alb2);
      const u16* gb = Bw + (size_t)(n0 + r4) * K + k0 + kseg * 8;
      GL16(gb, blb1);
      GL16(gb + (size_t)64 * K, blb2);
      if constexpr (EPI == 1) {
        const u16* gc = B2w + (size_t)(n0 + r4) * K + k0 + kseg * 8;
        GL16(gc, clb1);
        GL16(gc + (size_t)64 * K, clb2);
      }
    }
    __syncthreads();

    short8 af[4], bf[4], cf[4];
#pragma unroll
    for (int i = 0; i < 4; ++i) {
      af[i] = *(const short8*)(Al + ((size_t)(wm * 64 + i * 16 + fr) * 4 + kg) * 8);
      bf[i] = *(const short8*)(Bl + ((size_t)(wn * 64 + i * 16 + fr) * 4 + kg) * 8);
      if constexpr (EPI == 1)
        cf[i] = *(const short8*)(Cl + ((size_t)(wn * 64 + i * 16 + fr) * 4 + kg) * 8);
    }
#pragma unroll
    for (int mi = 0; mi < 4; ++mi)
#pragma unroll
      for (int ni = 0; ni < 4; ++ni) {
        acc[mi][ni] = __builtin_amdgcn_mfma_f32_16x16x32_bf16(af[mi], bf[ni], acc[mi][ni], 0, 0, 0);
        if constexpr (EPI == 1)
          acc2[mi][ni] =
              __builtin_amdgcn_mfma_f32_16x16x32_bf16(af[mi], cf[ni], acc2[mi][ni], 0, 0, 0);
      }
    __syncthreads();
  }

  // epilogue: C/D mapping col = lane&15, row = (lane>>4)*4 + reg  [m89-verified]
  const int r0 = m0 + wm * 64 + kg * 4;
  const int c0 = n0 + wn * 64 + fr;
  float ypart[16];
  if constexpr (EPI == 2) {
#pragma unroll
    for (int q = 0; q < 16; ++q) ypart[q] = 0.f;
  }
#pragma unroll
  for (int ni = 0; ni < 4; ++ni) {
    const int col = c0 + ni * 16;
    float b1 = 0.f, b2 = 0.f, cwv = 0.f;
    if constexpr (EPI == 1) { b1 = bias1[col]; b2 = bias2[col]; }
    if constexpr (EPI == 2) { b1 = 2.f * bias1[col]; cwv = cw[col]; }
#pragma unroll
    for (int mi = 0; mi < 4; ++mi) {
#pragma unroll
      for (int r = 0; r < 4; ++r) {
        const int row = r0 + mi * 16 + r;
        const float v = acc[mi][ni][r];
        if constexpr (EPI == 0) {
          Out[(size_t)row * H + col] = f2b(v);
        } else if constexpr (EPI == 1) {
          const float g = 1.f / (1.f + __expf(-(v + b1)));
          const float nn = acc2[mi][ni][r] + b2;
          const float x = b2f(Xres[(size_t)row * H + col]);
          Out[(size_t)row * H + col] = f2b(g * nn + (1.f - g) * x);
        } else {
          const float s = (v + b1) * rden[row];
          const float rl = s > 0.f ? s : 0.f;
          ypart[mi * 4 + r] += rl * cwv;
          Out[(size_t)row * H + col] = f2b(rl);
        }
      }
    }
  }
  if constexpr (EPI == 2) {
    // reduce ypart over the 16 lanes (fr) sharing each row, then 1 atomic/row
#pragma unroll
    for (int q = 0; q < 16; ++q) {
      float p = ypart[q];
      p += __shfl_xor(p, 1);
      p += __shfl_xor(p, 2);
      p += __shfl_xor(p, 4);
      p += __shfl_xor(p, 8);
      if (fr == 0) atomicAdd(&yv[r0 + (q >> 2) * 16 + (q & 3)], p);
    }
  }
}

// ---------------------------------------------------------------------------
// Semb [B][EMB][L] fp32 -> A0 [B*L][KPAD] bf16 (transpose + pad 400->416)
// ---------------------------------------------------------------------------
__global__ __launch_bounds__(256) void k_sembT(const float* __restrict__ Semb,
                                               u16* __restrict__ A0) {
  const int b = blockIdx.x, e0 = blockIdx.y * 64, l0 = blockIdx.z * 64;
  __shared__ u16 tile[64][72];
  const int t = threadIdx.x;
  {
    const int er = t >> 2, ls = (t & 3) * 16;
    if (e0 + er < EMB) {
      const float* src = Semb + ((size_t)b * EMB + e0 + er) * L + l0 + ls;
#pragma unroll
      for (int i = 0; i < 4; ++i) {
        const float4 v = *(const float4*)(src + i * 4);
        tile[er][ls + i * 4 + 0] = f2b(v.x);
        tile[er][ls + i * 4 + 1] = f2b(v.y);
        tile[er][ls + i * 4 + 2] = f2b(v.z);
        tile[er][ls + i * 4 + 3] = f2b(v.w);
      }
    } else {
#pragma unroll
      for (int i = 0; i < 16; ++i) tile[er][ls + i] = 0;
    }
  }
  __syncthreads();
  {
    const int lr = t >> 2, es = (t & 3) * 16;
    if (e0 + es < KPAD) {
      u16x8 v0, v1;
#pragma unroll
      for (int i = 0; i < 8; ++i) v0[i] = tile[es + i][lr];
#pragma unroll
      for (int i = 0; i < 8; ++i) v1[i] = tile[es + 8 + i][lr];
      u16* dst = A0 + (size_t)(b * L + l0 + lr) * KPAD + e0 + es;
      *(u16x8*)dst = v0;
      *(u16x8*)(dst + 8) = v1;
    }
  }
}

// generic fp32 -> bf16
__global__ void k_cvt(const float* __restrict__ in, u16* __restrict__ out, int n) {
  const int i = blockIdx.x * 256 + threadIdx.x;
  if (i < n) out[i] = f2b(in[i]);
}

// W1 [256][400] fp32 -> [256][416] bf16 padded
__global__ void k_cvt_w1(const float* __restrict__ W1, u16* __restrict__ out) {
  const int i = blockIdx.x * 256 + threadIdx.x;
  const int o = i / KPAD, k = i - o * KPAD;
  out[i] = (k < EMB) ? f2b(W1[o * EMB + k]) : (u16)0;
}

// dedup'd adjacency bitmap
__global__ void k_edges(const int* __restrict__ edges, unsigned* __restrict__ bm) {
  const int t = blockIdx.x * 256 + threadIdx.x;
  const int b = t >> 9, e = t & 511;
  const int u = edges[(size_t)(b * NE + e) * 2 + 0];
  const int v = edges[(size_t)(b * NE + e) * 2 + 1];
  atomicOr(&bm[(size_t)(b * L + u) * 16 + (v >> 5)], 1u << (v & 31));
  atomicOr(&bm[(size_t)(b * L + v) * 16 + (u >> 5)], 1u << (u & 31));
}

__global__ void k_rden(const unsigned* __restrict__ bm, float* __restrict__ rden) {
  const int m = blockIdx.x * 256 + threadIdx.x;
  const uint4* p = (const uint4*)(bm + (size_t)m * 16);
  int c = 0;
#pragma unroll
  for (int w = 0; w < 4; ++w) {
    const uint4 v = p[w];
    c += __popc(v.x) + __popc(v.y) + __popc(v.z) + __popc(v.w);
  }
  rden[m] = 1.f / (1.f + (float)c);
}

// T[m,:] = h[m,:] + sum_{s in adj row} h[s,:]
// 8 tokens/block, 32 lanes/token, u16x8 (16B) loads; neighbor rows are
// within the batch's 512-token x 512B = 256KB working set -> L2-resident.
__global__ __launch_bounds__(256) void k_gather(const unsigned* __restrict__ bm,
                                                const u16* __restrict__ h,
                                                u16* __restrict__ T) {
  const int t = threadIdx.x;
  const int tok = blockIdx.x * 8 + (t >> 5);
  const int b = tok >> 9;
  const int c = (t & 31) * 8;
  const uint4* wp4 = (const uint4*)(bm + (size_t)tok * 16);
  const uint4 w0 = wp4[0], w1 = wp4[1], w2 = wp4[2], w3 = wp4[3];
  const unsigned wa[16] = {w0.x, w0.y, w0.z, w0.w, w1.x, w1.y, w1.z, w1.w,
                           w2.x, w2.y, w2.z, w2.w, w3.x, w3.y, w3.z, w3.w};
  float acc[8];
  {
    const u16x8 v = *(const u16x8*)(h + (size_t)tok * H + c);
#pragma unroll
    for (int i = 0; i < 8; ++i) acc[i] = b2f(v[i]);
  }
#pragma unroll
  for (int wi = 0; wi < 16; ++wi) {
    unsigned bits = wa[wi];
    while (bits) {
      const int bit = __ffs(bits) - 1;
      bits &= bits - 1;
      const int s = wi * 32 + bit;
      const u16x8 u = *(const u16x8*)(h + (size_t)(b * L + s) * H + c);
#pragma unroll
      for (int i = 0; i < 8; ++i) acc[i] += b2f(u[i]);
    }
  }
  u16x8 o;
#pragma unroll
  for (int i = 0; i < 8; ++i) o[i] = f2b(acc[i]);
  *(u16x8*)(T + (size_t)tok * H + c) = o;
}

// logits[b,m] = maskS ? (sum_l relu(yv[b,l]+cb)*lin_W[m,l] + lin_b[m]) : -1e30
__global__ __launch_bounds__(256) void k_logits(const float* __restrict__ yv,
                                                const float* __restrict__ cb,
                                                const float* __restrict__ lw,
                                                const float* __restrict__ lb,
                                                const int* __restrict__ wids,
                                                float* __restrict__ out) {
  const int b = blockIdx.x >> 1;
  const int m = ((blockIdx.x & 1) << 8) + threadIdx.x;
  __shared__ float ys[512];
  const float cb0 = cb[0];
  ys[threadIdx.x] = fmaxf(yv[(size_t)b * L + threadIdx.x] + cb0, 0.f);
  ys[threadIdx.x + 256] = fmaxf(yv[(size_t)b * L + 256 + threadIdx.x] + cb0, 0.f);
  __syncthreads();
  float acc = lb[m];
  const float4* wr = (const float4*)(lw + (size_t)m * L);
#pragma unroll 4
  for (int l4 = 0; l4 < 128; ++l4) {
    const float4 w4 = wr[l4];
    acc += ys[l4 * 4] * w4.x + ys[l4 * 4 + 1] * w4.y + ys[l4 * 4 + 2] * w4.z +
           ys[l4 * 4 + 3] * w4.w;
  }
  out[(size_t)b * L + m] = (wids[(size_t)b * L + m] != 0) ? acc : -1.0e30f;
}

__global__ void k_maskA(const int* __restrict__ y1, const int* __restrict__ y2,
                        float* __restrict__ out) {
  const int t = blockIdx.x * 256 + threadIdx.x;
  const int b = t >> 5, j = t & 31;
  out[t] = (y1[b] + j <= y2[b]) ? 1.0f : 0.0f;
}

extern "C" void kernel_launch(void* const* d_in, const int* in_sizes, int n_in,
                              void* d_out, int out_size, void* d_ws, size_t ws_size,
                              hipStream_t stream) {
  (void)in_sizes; (void)n_in; (void)out_size; (void)ws_size;
  const float* Semb      = (const float*)d_in[0];
  const int*   wids      = (const int*)d_in[1];
  const int*   y1        = (const int*)d_in[2];
  const int*   y2        = (const int*)d_in[3];
  const int*   edges     = (const int*)d_in[4];
  const float* W1        = (const float*)d_in[5];
  const float* hw_lin_W  = (const float*)d_in[6];
  const float* hw_lin_b  = (const float*)d_in[7];
  const float* hw_gate_W = (const float*)d_in[8];
  const float* hw_gate_b = (const float*)d_in[9];
  const float* gcn_W     = (const float*)d_in[10];
  const float* gcn_b     = (const float*)d_in[11];
  const float* conv_W    = (const float*)d_in[12];
  const float* conv_b    = (const float*)d_in[13];
  const float* lin_W     = (const float*)d_in[14];
  const float* lin_b     = (const float*)d_in[15];
  float* out = (float*)d_out;

  char* ws = (char*)d_ws;
  const size_t SZA = (size_t)M_TOT * KPAD * 2;
  const size_t SZX = (size_t)M_TOT * H * 2;
  u16* A0   = (u16*)(ws);
  u16* P0b  = (u16*)(ws + SZA);
  u16* P1b  = (u16*)(ws + SZA + SZX);
  u16* O0   = (u16*)(ws + SZA + 2 * SZX);
  u16* O1   = (u16*)(ws + SZA + 3 * SZX);
  u16* O2   = (u16*)(ws + SZA + 4 * SZX);
  char* wp  = ws + SZA + 5 * SZX;
  u16* W1b  = (u16*)(wp);                         // 212,992
  u16* HWGb = (u16*)(wp + 212992);                // 262,144
  u16* HWLb = (u16*)(wp + 212992 + 262144);       // 262,144
  u16* GCNb = (u16*)(wp + 212992 + 2 * 262144);   // 393,216
  char* sp  = wp + 212992 + 2 * 262144 + 393216;
  unsigned* bm   = (unsigned*)(sp);               // 2 MB
  float*    yv   = (float*)(sp + 2097152);        // 128 KB (zeroed w/ bm)
  float*    rden = (float*)(sp + 2097152 + 131072);

  // adjacency + yv accumulator init (one memset covers bm and yv)
  hipMemsetAsync(bm, 0, 2097152 + 131072, stream);
  k_edges<<<dim3(B * NE / 256), 256, 0, stream>>>(edges, bm);
  k_rden<<<dim3(B * L / 256), 256, 0, stream>>>(bm, rden);

  // conversions
  k_cvt_w1<<<dim3(256 * KPAD / 256), 256, 0, stream>>>(W1, W1b);
  k_cvt<<<dim3(2 * H * H / 256), 256, 0, stream>>>(hw_gate_W, HWGb, 2 * H * H);
  k_cvt<<<dim3(2 * H * H / 256), 256, 0, stream>>>(hw_lin_W, HWLb, 2 * H * H);
  k_cvt<<<dim3(NL * H * H / 256), 256, 0, stream>>>(gcn_W, GCNb, NL * H * H);
  k_sembT<<<dim3(B, 7, 8), 256, 0, stream>>>(Semb, A0);

  // conv 1x1
  gemm128<0><<<dim3(M_TOT / 128, 2), 256, 0, stream>>>(A0, W1b, nullptr, KPAD, nullptr, nullptr,
                                                       nullptr, nullptr, nullptr, nullptr, P0b);
  // highway x2
  gemm128<1><<<dim3(M_TOT / 128, 2), 256, 0, stream>>>(P0b, HWGb, HWLb, H, hw_gate_b, hw_lin_b,
                                                       P0b, nullptr, nullptr, nullptr, P1b);
  gemm128<1><<<dim3(M_TOT / 128, 2), 256, 0, stream>>>(P1b, HWGb + H * H, HWLb + H * H, H,
                                                       hw_gate_b + H, hw_lin_b + H, P1b, nullptr,
                                                       nullptr, nullptr, P0b);
  // GCN layers (epilogue accumulates yv += relu_out . conv_W[l])
  const u16* hin = P0b;
  u16* outs[3] = {O0, O1, O2};
  for (int l = 0; l < NL; ++l) {
    k_gather<<<dim3(M_TOT / 8), 256, 0, stream>>>(bm, hin, P1b);
    gemm128<2><<<dim3(M_TOT / 128, 2), 256, 0, stream>>>(P1b, GCNb + l * H * H, nullptr, H,
                                                         gcn_b + l * H, nullptr, nullptr, rden,
                                                         conv_W + l * H, yv, outs[l]);
    hin = outs[l];
  }

  // head
  k_logits<<<dim3(B * 2), 256, 0, stream>>>(yv, conv_b, lin_W, lin_b, wids, out);
  k_maskA<<<dim3(B * MAXA / 256), 256, 0, stream>>>(y1, y2, out + B * L);
}